// Round 3
// baseline (964.246 us; speedup 1.0000x reference)
//
#include <hip/hip_runtime.h>
#include <stdint.h>

typedef unsigned short ushort_t;
typedef short s16x8 __attribute__((ext_vector_type(8)));
typedef float f32x4 __attribute__((ext_vector_type(4)));

#define S_LEN 4096
#define D_DIM 1024
#define H_DIM 2816
#define E_NUM 8
#define ROWS_CAP 9216  // 8192 real rows + up to 8*127 pad, rounded

// ---- workspace layout (bytes) ----
#define OFF_CTL      0         // counts[8] @0, cursor[8] @64, baseP[8] @128, countP[8] @192
#define OFF_ROWTOK   1024      // int[ROWS_CAP]   (must be zeroed: pad rows -> token 0)
#define OFF_TOKE     81920     // int[S*2]
#define OFF_TOKG     114688    // float[S*2]
#define OFF_TOKROW   147456    // int[S*2]  token -> row  (inverse map for combine)
#define OFF_XG       262144                                  // bf16 [ROWS_CAP][D]
#define OFF_HBUF     (OFF_XG + (size_t)ROWS_CAP*D_DIM*2)     // bf16 [ROWS_CAP][H]
#define OFF_W1BT     (OFF_HBUF + (size_t)ROWS_CAP*H_DIM*2)   // bf16 [E][H][D]  (w1 transposed)
#define OFF_W2BT     (OFF_W1BT + (size_t)E_NUM*D_DIM*H_DIM*2)// bf16 [E][D][H]  (w2 transposed)
// rowout (fp32 [ROWS_CAP][D] = 37.7MB) ALIASES w1bT (46.1MB): w1bT is dead after gemm1.
#define OFF_ROWOUT   OFF_W1BT

__device__ __forceinline__ ushort_t f2bf(float f) {
  unsigned int u = __float_as_uint(f);
  unsigned int r = (u + 0x7fffu + ((u >> 16) & 1u)) >> 16;
  return (ushort_t)r;
}

__device__ __forceinline__ void g2l16(const void* g, void* l) {
  __builtin_amdgcn_global_load_lds((const __attribute__((address_space(1))) void*)g,
                                   (__attribute__((address_space(3))) void*)l, 16, 0, 0);
}

// ---------- gating: logits -> top2 -> softmax -> counts ----------
__global__ void gate_kernel(const float* __restrict__ x, const float* __restrict__ wg,
                            const float* __restrict__ bg, int* __restrict__ tok_e,
                            float* __restrict__ tok_g, int* __restrict__ ctl) {
  int wave = threadIdx.x >> 6;
  int lane = threadIdx.x & 63;
  int s = blockIdx.x * 4 + wave;
  float acc[8];
#pragma unroll
  for (int e = 0; e < 8; e++) acc[e] = 0.f;
  const float* xr = x + (size_t)s * D_DIM;
  for (int d = lane; d < D_DIM; d += 64) {
    float xv = xr[d];
    const float4* w = (const float4*)(wg + (size_t)d * 8);
    float4 w0 = w[0], w1 = w[1];
    acc[0] += xv * w0.x; acc[1] += xv * w0.y; acc[2] += xv * w0.z; acc[3] += xv * w0.w;
    acc[4] += xv * w1.x; acc[5] += xv * w1.y; acc[6] += xv * w1.z; acc[7] += xv * w1.w;
  }
#pragma unroll
  for (int e = 0; e < 8; e++) {
    for (int off = 32; off > 0; off >>= 1) acc[e] += __shfl_xor(acc[e], off, 64);
  }
  if (lane == 0) {
    float l[8];
#pragma unroll
    for (int e = 0; e < 8; e++) l[e] = acc[e] + bg[e];
    int e0 = 0;
#pragma unroll
    for (int e = 1; e < 8; e++) if (l[e] > l[e0]) e0 = e;
    int e1 = (e0 == 0) ? 1 : 0;
#pragma unroll
    for (int e = 0; e < 8; e++) if (e != e0 && l[e] > l[e1]) e1 = e;
    float t = __expf(l[e1] - l[e0]);   // <= 1
    float p1 = t / (1.f + t);
    float p0 = 1.f - p1;
    tok_e[s * 2] = e0; tok_e[s * 2 + 1] = e1;
    tok_g[s * 2] = p0; tok_g[s * 2 + 1] = p1;
    atomicAdd(&ctl[e0], 1);
    atomicAdd(&ctl[e1], 1);
  }
}

// ---------- prefix scan over 8 experts, 128-padded ----------
__global__ void scan_kernel(int* ctl) {
  if (threadIdx.x == 0 && blockIdx.x == 0) {
    int run = 0;
    for (int e = 0; e < 8; e++) {
      int cp = (ctl[e] + 127) & ~127;
      ctl[32 + e] = run;   // baseP
      ctl[48 + e] = cp;    // countP
      run += cp;
    }
  }
}

// ---------- slot assignment (also builds inverse map token->row) ----------
__global__ void assign_kernel(const int* __restrict__ tok_e, int* ctl,
                              int* __restrict__ row_token, int* __restrict__ tok_row) {
  int i = blockIdx.x * blockDim.x + threadIdx.x;  // 0..8191  (= s*2+k)
  int e = tok_e[i];
  int slot = atomicAdd(&ctl[16 + e], 1);          // cursor
  int row = ctl[32 + e] + slot;                   // baseP
  row_token[row] = i >> 1;
  tok_row[i] = row;
}

// ---------- gather x rows into expert-sorted bf16 ----------
__global__ void gather_kernel(const float* __restrict__ x, const int* __restrict__ row_token,
                              ushort_t* __restrict__ xg) {
  int row = blockIdx.x;
  int t = row_token[row];                          // pad rows: 0 (harmless)
  float4 v = ((const float4*)(x + (size_t)t * D_DIM))[threadIdx.x];
  uint2 o;
  o.x = (unsigned)f2bf(v.x) | ((unsigned)f2bf(v.y) << 16);
  o.y = (unsigned)f2bf(v.z) | ((unsigned)f2bf(v.w) << 16);
  *(uint2*)(xg + (size_t)row * D_DIM + threadIdx.x * 4) = o;
}

// ---------- fp32 [E][R][C] -> bf16 [E][C][R] transpose+convert (64-row tiles, uint writes) ----------
__global__ void convT_kernel(const float* __restrict__ in, ushort_t* __restrict__ out,
                             int R, int C) {
  __shared__ float t[64][33];
  size_t base = (size_t)blockIdx.z * R * C;
  int c = blockIdx.x * 32 + threadIdx.x;
#pragma unroll
  for (int i = 0; i < 64; i += 8) {
    int r = blockIdx.y * 64 + threadIdx.y + i;
    t[threadIdx.y + i][threadIdx.x] = in[base + (size_t)r * C + c];
  }
  __syncthreads();
  int rr = blockIdx.y * 64 + threadIdx.x * 2;
#pragma unroll
  for (int i = 0; i < 32; i += 8) {
    int cc = blockIdx.x * 32 + threadIdx.y + i;
    unsigned lo = f2bf(t[threadIdx.x * 2][threadIdx.y + i]);
    unsigned hi = f2bf(t[threadIdx.x * 2 + 1][threadIdx.y + i]);
    *(unsigned*)(out + base + (size_t)cc * R + rr) = lo | (hi << 16);
  }
}

// ---------- GEMM1: h = silu(xg @ w1^T-tile + b1), bf16 out ----------
// 128x64 tile, 4 waves as 2x2 (each 64 rows x 32 cols).
// mfma(b, a): D lane = token row, D regs = 4 consecutive H cols -> packed uint2 stores.
__global__ __launch_bounds__(256) void gemm1_kernel(
    const ushort_t* __restrict__ xg, const ushort_t* __restrict__ w1bT,
    const float* __restrict__ b1, ushort_t* __restrict__ hbuf, const int* __restrict__ ctl) {
  int e = blockIdx.z;
  int cp = ctl[48 + e];
  if ((int)blockIdx.x * 128 >= cp) return;
  int rowbase = ctl[32 + e] + blockIdx.x * 128;
  const ushort_t* Ab = xg + (size_t)rowbase * D_DIM;
  const ushort_t* Bb = w1bT + ((size_t)e * H_DIM + (size_t)blockIdx.y * 64) * D_DIM;

  __shared__ __align__(16) short As[128 * 32];   // 8 KB
  __shared__ __align__(16) short Bs[64 * 32];    // 4 KB

  int tid = threadIdx.x;
  int wave = tid >> 6, lane = tid & 63;
  int wm = wave >> 1, wn = wave & 1;
  int m16 = lane & 15, quad = lane >> 4;

  f32x4 acc[4][2];
#pragma unroll
  for (int i = 0; i < 4; i++)
#pragma unroll
    for (int j = 0; j < 2; j++) acc[i][j] = (f32x4){0.f, 0.f, 0.f, 0.f};

  int srow = wave * 16 + (lane >> 2);       // staging row for this lane
  int scol = (lane & 3) * 8;                // staging col (8 bf16 = 16B)

  for (int k0 = 0; k0 < D_DIM; k0 += 32) {
    g2l16(Ab + (size_t)srow * D_DIM + k0 + scol, As + (wave * 16) * 32);
    g2l16(Ab + (size_t)(srow + 64) * D_DIM + k0 + scol, As + (64 + wave * 16) * 32);
    g2l16(Bb + (size_t)srow * D_DIM + k0 + scol, Bs + (wave * 16) * 32);
    __syncthreads();
    s16x8 a[4], b[2];
#pragma unroll
    for (int i = 0; i < 4; i++)
      a[i] = *(const s16x8*)(As + ((wm * 64 + i * 16 + m16) * 32 + quad * 8));
#pragma unroll
    for (int j = 0; j < 2; j++)
      b[j] = *(const s16x8*)(Bs + ((wn * 32 + j * 16 + m16) * 32 + quad * 8));
#pragma unroll
    for (int i = 0; i < 4; i++)
#pragma unroll
      for (int j = 0; j < 2; j++)
        acc[i][j] = __builtin_amdgcn_mfma_f32_16x16x32_bf16(b[j], a[i], acc[i][j], 0, 0, 0);
    __syncthreads();
  }

  int nbase = blockIdx.y * 64 + wn * 32;
  const float* b1e = b1 + (size_t)e * H_DIM;
#pragma unroll
  for (int i = 0; i < 4; i++) {
    int rowg = rowbase + wm * 64 + i * 16 + m16;
#pragma unroll
    for (int j = 0; j < 2; j++) {
      int h = nbase + j * 16 + quad * 4;
      float4 bb = *(const float4*)(b1e + h);
      float v0 = acc[i][j][0] + bb.x, v1 = acc[i][j][1] + bb.y;
      float v2 = acc[i][j][2] + bb.z, v3 = acc[i][j][3] + bb.w;
      v0 = v0 / (1.f + __expf(-v0)); v1 = v1 / (1.f + __expf(-v1));
      v2 = v2 / (1.f + __expf(-v2)); v3 = v3 / (1.f + __expf(-v3));
      uint2 o;
      o.x = (unsigned)f2bf(v0) | ((unsigned)f2bf(v1) << 16);
      o.y = (unsigned)f2bf(v2) | ((unsigned)f2bf(v3) << 16);
      *(uint2*)(hbuf + (size_t)rowg * H_DIM + h) = o;
    }
  }
}

// ---------- GEMM2: rowout[row] = h[row] @ w2-tile  (float4 stores) ----------
__global__ __launch_bounds__(256) void gemm2_kernel(
    const ushort_t* __restrict__ hbuf, const ushort_t* __restrict__ w2bT,
    float* __restrict__ rowout, const int* __restrict__ ctl) {
  int e = blockIdx.z;
  int cp = ctl[48 + e];
  if ((int)blockIdx.x * 128 >= cp) return;
  int rowbase = ctl[32 + e] + blockIdx.x * 128;
  const ushort_t* Ab = hbuf + (size_t)rowbase * H_DIM;
  const ushort_t* Bb = w2bT + ((size_t)e * D_DIM + (size_t)blockIdx.y * 64) * H_DIM;

  __shared__ __align__(16) short As[128 * 32];
  __shared__ __align__(16) short Bs[64 * 32];

  int tid = threadIdx.x;
  int wave = tid >> 6, lane = tid & 63;
  int wm = wave >> 1, wn = wave & 1;
  int m16 = lane & 15, quad = lane >> 4;

  f32x4 acc[4][2];
#pragma unroll
  for (int i = 0; i < 4; i++)
#pragma unroll
    for (int j = 0; j < 2; j++) acc[i][j] = (f32x4){0.f, 0.f, 0.f, 0.f};

  int srow = wave * 16 + (lane >> 2);
  int scol = (lane & 3) * 8;

  for (int k0 = 0; k0 < H_DIM; k0 += 32) {
    g2l16(Ab + (size_t)srow * H_DIM + k0 + scol, As + (wave * 16) * 32);
    g2l16(Ab + (size_t)(srow + 64) * H_DIM + k0 + scol, As + (64 + wave * 16) * 32);
    g2l16(Bb + (size_t)srow * H_DIM + k0 + scol, Bs + (wave * 16) * 32);
    __syncthreads();
    s16x8 a[4], b[2];
#pragma unroll
    for (int i = 0; i < 4; i++)
      a[i] = *(const s16x8*)(As + ((wm * 64 + i * 16 + m16) * 32 + quad * 8));
#pragma unroll
    for (int j = 0; j < 2; j++)
      b[j] = *(const s16x8*)(Bs + ((wn * 32 + j * 16 + m16) * 32 + quad * 8));
#pragma unroll
    for (int i = 0; i < 4; i++)
#pragma unroll
      for (int j = 0; j < 2; j++)
        acc[i][j] = __builtin_amdgcn_mfma_f32_16x16x32_bf16(b[j], a[i], acc[i][j], 0, 0, 0);
    __syncthreads();
  }

  int nbase = blockIdx.y * 64 + wn * 32;
#pragma unroll
  for (int i = 0; i < 4; i++) {
    int rowg = rowbase + wm * 64 + i * 16 + m16;
#pragma unroll
    for (int j = 0; j < 2; j++) {
      int d = nbase + j * 16 + quad * 4;
      *(f32x4*)(rowout + (size_t)rowg * D_DIM + d) = acc[i][j];
    }
  }
}

// ---------- combine: out[s] = sum_k g_k * (rowout[row_k] + b2[e_k]) ----------
__global__ void combine_kernel(const float* __restrict__ rowout, const float* __restrict__ b2,
                               const int* __restrict__ tok_e, const float* __restrict__ tok_g,
                               const int* __restrict__ tok_row, float* __restrict__ out) {
  int s = blockIdx.x;
  int e0 = tok_e[s * 2], e1 = tok_e[s * 2 + 1];
  float g0 = tok_g[s * 2], g1 = tok_g[s * 2 + 1];
  int r0 = tok_row[s * 2], r1 = tok_row[s * 2 + 1];
  int d = threadIdx.x * 4;
  float4 a = *(const float4*)(rowout + (size_t)r0 * D_DIM + d);
  float4 b = *(const float4*)(rowout + (size_t)r1 * D_DIM + d);
  float4 c0 = *(const float4*)(b2 + (size_t)e0 * D_DIM + d);
  float4 c1 = *(const float4*)(b2 + (size_t)e1 * D_DIM + d);
  float4 o;
  o.x = g0 * (a.x + c0.x) + g1 * (b.x + c1.x);
  o.y = g0 * (a.y + c0.y) + g1 * (b.y + c1.y);
  o.z = g0 * (a.z + c0.z) + g1 * (b.z + c1.z);
  o.w = g0 * (a.w + c0.w) + g1 * (b.w + c1.w);
  *(float4*)(out + (size_t)s * D_DIM + d) = o;
}

extern "C" void kernel_launch(void* const* d_in, const int* in_sizes, int n_in,
                              void* d_out, int out_size, void* d_ws, size_t ws_size,
                              hipStream_t stream) {
  const float* x      = (const float*)d_in[0];
  const float* w_gate = (const float*)d_in[1];
  const float* b_gate = (const float*)d_in[2];
  const float* w1     = (const float*)d_in[3];
  const float* b1     = (const float*)d_in[4];
  const float* w2     = (const float*)d_in[5];
  const float* b2     = (const float*)d_in[6];
  float* out = (float*)d_out;
  char* ws = (char*)d_ws;

  int*      ctl       = (int*)(ws + OFF_CTL);
  int*      row_token = (int*)(ws + OFF_ROWTOK);
  int*      tok_e     = (int*)(ws + OFF_TOKE);
  float*    tok_g     = (float*)(ws + OFF_TOKG);
  int*      tok_row   = (int*)(ws + OFF_TOKROW);
  ushort_t* xg        = (ushort_t*)(ws + OFF_XG);
  ushort_t* hbuf      = (ushort_t*)(ws + OFF_HBUF);
  ushort_t* w1bT      = (ushort_t*)(ws + OFF_W1BT);
  ushort_t* w2bT      = (ushort_t*)(ws + OFF_W2BT);
  float*    rowout    = (float*)(ws + OFF_ROWOUT);  // aliases w1bT (dead after gemm1)

  // zero ctl + row_token (pad rows must map to token 0; ws is poisoned 0xAA)
  hipMemsetAsync(ws, 0, 40960, stream);

  gate_kernel<<<S_LEN / 4, 256, 0, stream>>>(x, w_gate, b_gate, tok_e, tok_g, ctl);
  scan_kernel<<<1, 64, 0, stream>>>(ctl);
  assign_kernel<<<32, 256, 0, stream>>>(tok_e, ctl, row_token, tok_row);
  gather_kernel<<<ROWS_CAP, 256, 0, stream>>>(x, row_token, xg);
  convT_kernel<<<dim3(H_DIM / 32, D_DIM / 64, E_NUM), dim3(32, 8), 0, stream>>>(w1, w1bT, D_DIM, H_DIM);
  convT_kernel<<<dim3(D_DIM / 32, H_DIM / 64, E_NUM), dim3(32, 8), 0, stream>>>(w2, w2bT, H_DIM, D_DIM);
  gemm1_kernel<<<dim3(32, H_DIM / 64, E_NUM), 256, 0, stream>>>(xg, w1bT, b1, hbuf, ctl);
  gemm2_kernel<<<dim3(32, D_DIM / 64, E_NUM), 256, 0, stream>>>(hbuf, w2bT, rowout, ctl);
  combine_kernel<<<S_LEN, 256, 0, stream>>>(rowout, b2, tok_e, tok_g, tok_row, out);
}

// Round 4
// 585.109 us; speedup vs baseline: 1.6480x; 1.6480x over previous
//
#include <hip/hip_runtime.h>
#include <stdint.h>

typedef unsigned short ushort_t;
typedef short s16x8 __attribute__((ext_vector_type(8)));
typedef float f32x4 __attribute__((ext_vector_type(4)));

#define S_LEN 4096
#define D_DIM 1024
#define H_DIM 2816
#define E_NUM 8
#define ROWS_CAP 9216   // 72 * 128
#define MBLK 72
#define LDSPAD 72       // 64 + 8 shorts -> 144B row stride (16B aligned, bank-spread)

// ---- workspace layout (bytes) ----
#define OFF_CTL      0         // counts[8]@0, cursor[8]@64, baseP[8]@128, countP[8]@192, mblk_e[72]@256
#define OFF_ROWTOK   1024      // int[ROWS_CAP]   (zeroed: pad rows -> token 0)
#define OFF_TOKE     81920     // int[S*2]
#define OFF_TOKG     114688    // float[S*2]
#define OFF_TOKROW   147456    // int[S*2]
#define OFF_XG       262144                                  // bf16 [ROWS_CAP][D]
#define OFF_HBUF     (OFF_XG + (size_t)ROWS_CAP*D_DIM*2)     // bf16 [ROWS_CAP][H]
#define OFF_W1BT     (OFF_HBUF + (size_t)ROWS_CAP*H_DIM*2)   // bf16 [E][H][D]
#define OFF_W2BT     (OFF_W1BT + (size_t)E_NUM*D_DIM*H_DIM*2)// bf16 [E][D][H]
#define OFF_ROWOUT   OFF_W1BT  // fp32 [ROWS_CAP][D] aliases w1bT (dead after gemm1)

__device__ __forceinline__ ushort_t f2bf(float f) {
  unsigned int u = __float_as_uint(f);
  unsigned int r = (u + 0x7fffu + ((u >> 16) & 1u)) >> 16;
  return (ushort_t)r;
}

// ---------- gating ----------
__global__ void gate_kernel(const float* __restrict__ x, const float* __restrict__ wg,
                            const float* __restrict__ bg, int* __restrict__ tok_e,
                            float* __restrict__ tok_g, int* __restrict__ ctl) {
  int wave = threadIdx.x >> 6;
  int lane = threadIdx.x & 63;
  int s = blockIdx.x * 4 + wave;
  float acc[8];
#pragma unroll
  for (int e = 0; e < 8; e++) acc[e] = 0.f;
  const float* xr = x + (size_t)s * D_DIM;
  for (int d = lane; d < D_DIM; d += 64) {
    float xv = xr[d];
    const float4* w = (const float4*)(wg + (size_t)d * 8);
    float4 w0 = w[0], w1 = w[1];
    acc[0] += xv * w0.x; acc[1] += xv * w0.y; acc[2] += xv * w0.z; acc[3] += xv * w0.w;
    acc[4] += xv * w1.x; acc[5] += xv * w1.y; acc[6] += xv * w1.z; acc[7] += xv * w1.w;
  }
#pragma unroll
  for (int e = 0; e < 8; e++) {
    for (int off = 32; off > 0; off >>= 1) acc[e] += __shfl_xor(acc[e], off, 64);
  }
  if (lane == 0) {
    float l[8];
#pragma unroll
    for (int e = 0; e < 8; e++) l[e] = acc[e] + bg[e];
    int e0 = 0;
#pragma unroll
    for (int e = 1; e < 8; e++) if (l[e] > l[e0]) e0 = e;
    int e1 = (e0 == 0) ? 1 : 0;
#pragma unroll
    for (int e = 0; e < 8; e++) if (e != e0 && l[e] > l[e1]) e1 = e;
    float t = __expf(l[e1] - l[e0]);
    float p1 = t / (1.f + t);
    float p0 = 1.f - p1;
    tok_e[s * 2] = e0; tok_e[s * 2 + 1] = e1;
    tok_g[s * 2] = p0; tok_g[s * 2 + 1] = p1;
    atomicAdd(&ctl[e0], 1);
    atomicAdd(&ctl[e1], 1);
  }
}

// ---------- scan: 128-padded prefix + block->expert map ----------
__global__ void scan_kernel(int* ctl) {
  if (threadIdx.x == 0 && blockIdx.x == 0) {
    int run = 0;
    for (int e = 0; e < 8; e++) {
      int cp = (ctl[e] + 127) & ~127;
      ctl[32 + e] = run;   // baseP
      ctl[48 + e] = cp;    // countP
      run += cp;
    }
    for (int m = 0; m < MBLK; m++) {
      int r = m * 128, e = -1;
      if (r < run) {
        for (int q = 0; q < 8; q++)
          if (r >= ctl[32 + q] && r < ctl[32 + q] + ctl[48 + q]) { e = q; break; }
      }
      ctl[64 + m] = e;
    }
  }
}

// ---------- slot assignment ----------
__global__ void assign_kernel(const int* __restrict__ tok_e, int* ctl,
                              int* __restrict__ row_token, int* __restrict__ tok_row) {
  int i = blockIdx.x * blockDim.x + threadIdx.x;
  int e = tok_e[i];
  int slot = atomicAdd(&ctl[16 + e], 1);
  int row = ctl[32 + e] + slot;
  row_token[row] = i >> 1;
  tok_row[i] = row;
}

// ---------- gather x rows into expert-sorted bf16 ----------
__global__ void gather_kernel(const float* __restrict__ x, const int* __restrict__ row_token,
                              ushort_t* __restrict__ xg) {
  int row = blockIdx.x;
  int t = row_token[row];
  float4 v = ((const float4*)(x + (size_t)t * D_DIM))[threadIdx.x];
  uint2 o;
  o.x = (unsigned)f2bf(v.x) | ((unsigned)f2bf(v.y) << 16);
  o.y = (unsigned)f2bf(v.z) | ((unsigned)f2bf(v.w) << 16);
  *(uint2*)(xg + (size_t)row * D_DIM + threadIdx.x * 4) = o;
}

// ---------- fp32 [E][R][C] -> bf16 [E][C][R] ----------
__global__ void convT_kernel(const float* __restrict__ in, ushort_t* __restrict__ out,
                             int R, int C) {
  __shared__ float t[64][33];
  size_t base = (size_t)blockIdx.z * R * C;
  int c = blockIdx.x * 32 + threadIdx.x;
#pragma unroll
  for (int i = 0; i < 64; i += 8) {
    int r = blockIdx.y * 64 + threadIdx.y + i;
    t[threadIdx.y + i][threadIdx.x] = in[base + (size_t)r * C + c];
  }
  __syncthreads();
  int rr = blockIdx.y * 64 + threadIdx.x * 2;
#pragma unroll
  for (int i = 0; i < 32; i += 8) {
    int cc = blockIdx.x * 32 + threadIdx.y + i;
    unsigned lo = f2bf(t[threadIdx.x * 2][threadIdx.y + i]);
    unsigned hi = f2bf(t[threadIdx.x * 2 + 1][threadIdx.y + i]);
    *(unsigned*)(out + base + (size_t)cc * R + rr) = lo | (hi << 16);
  }
}

// ================= register-pipelined 128x128xBK64 GEMM bodies =================
// Staging: VGPR regs -> ds_write_b128 into padded LDS; next tile's global loads
// issued AFTER the write barrier so they stay in flight through ds_read+MFMA.
// mfma(b,a): acc lane = token row (m16), acc regs = 4 consecutive N cols.

#define GEMM_PIPE(KDIM)                                                          \
  __shared__ __align__(16) short As[128 * LDSPAD];                               \
  __shared__ __align__(16) short Bs[128 * LDSPAD];                               \
  int tid = threadIdx.x;                                                         \
  int wave = tid >> 6, lane = tid & 63;                                          \
  int wm = wave >> 1, wn = wave & 1;                                             \
  int m16 = lane & 15, quad = lane >> 4;                                         \
  int srow = lane >> 3;          /* 0..7 */                                      \
  int scol = (lane & 7) * 8;     /* shorts, 16B chunks */                        \
  const ushort_t* Ap = Ab + (size_t)(wave * 32 + srow) * KDIM + scol;            \
  const ushort_t* Bp = Bb + (size_t)(wave * 32 + srow) * KDIM + scol;            \
  short* Aw = As + (wave * 32 + srow) * LDSPAD + scol;                           \
  short* Bw = Bs + (wave * 32 + srow) * LDSPAD + scol;                           \
  f32x4 acc[4][4];                                                               \
  _Pragma("unroll") for (int i = 0; i < 4; i++)                                  \
  _Pragma("unroll") for (int j = 0; j < 4; j++)                                  \
      acc[i][j] = (f32x4){0.f, 0.f, 0.f, 0.f};                                   \
  s16x8 Ar[4], Br[4];                                                            \
  _Pragma("unroll") for (int c = 0; c < 4; c++) {                                \
    Ar[c] = *(const s16x8*)(Ap + (size_t)c * 8 * KDIM);                          \
    Br[c] = *(const s16x8*)(Bp + (size_t)c * 8 * KDIM);                          \
  }                                                                              \
  const int nk = KDIM / 64;                                                      \
  for (int it = 0; it < nk; ++it) {                                              \
    __syncthreads();                                                             \
    _Pragma("unroll") for (int c = 0; c < 4; c++) {                              \
      *(s16x8*)(Aw + c * 8 * LDSPAD) = Ar[c];                                    \
      *(s16x8*)(Bw + c * 8 * LDSPAD) = Br[c];                                    \
    }                                                                            \
    __syncthreads();                                                             \
    if (it + 1 < nk) {                                                           \
      const ushort_t* Ap2 = Ap + (it + 1) * 64;                                  \
      const ushort_t* Bp2 = Bp + (it + 1) * 64;                                  \
      _Pragma("unroll") for (int c = 0; c < 4; c++) {                            \
        Ar[c] = *(const s16x8*)(Ap2 + (size_t)c * 8 * KDIM);                     \
        Br[c] = *(const s16x8*)(Bp2 + (size_t)c * 8 * KDIM);                     \
      }                                                                          \
    }                                                                            \
    _Pragma("unroll") for (int kc = 0; kc < 2; kc++) {                           \
      s16x8 a[4], b[4];                                                          \
      _Pragma("unroll") for (int i = 0; i < 4; i++)                              \
        a[i] = *(const s16x8*)(As + (wm * 64 + i * 16 + m16) * LDSPAD +          \
                               kc * 32 + quad * 8);                              \
      _Pragma("unroll") for (int j = 0; j < 4; j++)                              \
        b[j] = *(const s16x8*)(Bs + (wn * 64 + j * 16 + m16) * LDSPAD +          \
                               kc * 32 + quad * 8);                              \
      _Pragma("unroll") for (int i = 0; i < 4; i++)                              \
      _Pragma("unroll") for (int j = 0; j < 4; j++)                              \
          acc[i][j] = __builtin_amdgcn_mfma_f32_16x16x32_bf16(b[j], a[i],        \
                                                              acc[i][j], 0, 0, 0);\
    }                                                                            \
  }

// ---------- GEMM1: h = silu(xg @ w1bT-tile + b1) ----------
__global__ __launch_bounds__(256) void gemm1_kernel(
    const ushort_t* __restrict__ xg, const ushort_t* __restrict__ w1bT,
    const float* __restrict__ b1, ushort_t* __restrict__ hbuf, const int* __restrict__ ctl) {
  int e = ctl[64 + blockIdx.x];
  if (e < 0) return;
  int rowbase = blockIdx.x * 128;
  const ushort_t* Ab = xg + (size_t)rowbase * D_DIM;
  const ushort_t* Bb = w1bT + ((size_t)e * H_DIM + (size_t)blockIdx.y * 128) * D_DIM;

  GEMM_PIPE(D_DIM)

  const float* b1e = b1 + (size_t)e * H_DIM;
#pragma unroll
  for (int i = 0; i < 4; i++) {
    int rowg = rowbase + wm * 64 + i * 16 + m16;
#pragma unroll
    for (int j = 0; j < 4; j++) {
      int h = blockIdx.y * 128 + wn * 64 + j * 16 + quad * 4;
      float4 bb = *(const float4*)(b1e + h);
      float v0 = acc[i][j][0] + bb.x, v1 = acc[i][j][1] + bb.y;
      float v2 = acc[i][j][2] + bb.z, v3 = acc[i][j][3] + bb.w;
      v0 = v0 / (1.f + __expf(-v0)); v1 = v1 / (1.f + __expf(-v1));
      v2 = v2 / (1.f + __expf(-v2)); v3 = v3 / (1.f + __expf(-v3));
      uint2 o;
      o.x = (unsigned)f2bf(v0) | ((unsigned)f2bf(v1) << 16);
      o.y = (unsigned)f2bf(v2) | ((unsigned)f2bf(v3) << 16);
      *(uint2*)(hbuf + (size_t)rowg * H_DIM + h) = o;
    }
  }
}

// ---------- GEMM2: rowout = h @ w2bT-tile ----------
__global__ __launch_bounds__(256) void gemm2_kernel(
    const ushort_t* __restrict__ hbuf, const ushort_t* __restrict__ w2bT,
    float* __restrict__ rowout, const int* __restrict__ ctl) {
  int e = ctl[64 + blockIdx.x];
  if (e < 0) return;
  int rowbase = blockIdx.x * 128;
  const ushort_t* Ab = hbuf + (size_t)rowbase * H_DIM;
  const ushort_t* Bb = w2bT + ((size_t)e * D_DIM + (size_t)blockIdx.y * 128) * H_DIM;

  GEMM_PIPE(H_DIM)

#pragma unroll
  for (int i = 0; i < 4; i++) {
    int rowg = rowbase + wm * 64 + i * 16 + m16;
#pragma unroll
    for (int j = 0; j < 4; j++) {
      int d = blockIdx.y * 128 + wn * 64 + j * 16 + quad * 4;
      *(f32x4*)(rowout + (size_t)rowg * D_DIM + d) = acc[i][j];
    }
  }
}

// ---------- combine ----------
__global__ void combine_kernel(const float* __restrict__ rowout, const float* __restrict__ b2,
                               const int* __restrict__ tok_e, const float* __restrict__ tok_g,
                               const int* __restrict__ tok_row, float* __restrict__ out) {
  int s = blockIdx.x;
  int e0 = tok_e[s * 2], e1 = tok_e[s * 2 + 1];
  float g0 = tok_g[s * 2], g1 = tok_g[s * 2 + 1];
  int r0 = tok_row[s * 2], r1 = tok_row[s * 2 + 1];
  int d = threadIdx.x * 4;
  float4 a = *(const float4*)(rowout + (size_t)r0 * D_DIM + d);
  float4 b = *(const float4*)(rowout + (size_t)r1 * D_DIM + d);
  float4 c0 = *(const float4*)(b2 + (size_t)e0 * D_DIM + d);
  float4 c1 = *(const float4*)(b2 + (size_t)e1 * D_DIM + d);
  float4 o;
  o.x = g0 * (a.x + c0.x) + g1 * (b.x + c1.x);
  o.y = g0 * (a.y + c0.y) + g1 * (b.y + c1.y);
  o.z = g0 * (a.z + c0.z) + g1 * (b.z + c1.z);
  o.w = g0 * (a.w + c0.w) + g1 * (b.w + c1.w);
  *(float4*)(out + (size_t)s * D_DIM + d) = o;
}

extern "C" void kernel_launch(void* const* d_in, const int* in_sizes, int n_in,
                              void* d_out, int out_size, void* d_ws, size_t ws_size,
                              hipStream_t stream) {
  const float* x      = (const float*)d_in[0];
  const float* w_gate = (const float*)d_in[1];
  const float* b_gate = (const float*)d_in[2];
  const float* w1     = (const float*)d_in[3];
  const float* b1     = (const float*)d_in[4];
  const float* w2     = (const float*)d_in[5];
  const float* b2     = (const float*)d_in[6];
  float* out = (float*)d_out;
  char* ws = (char*)d_ws;

  int*      ctl       = (int*)(ws + OFF_CTL);
  int*      row_token = (int*)(ws + OFF_ROWTOK);
  int*      tok_e     = (int*)(ws + OFF_TOKE);
  float*    tok_g     = (float*)(ws + OFF_TOKG);
  int*      tok_row   = (int*)(ws + OFF_TOKROW);
  ushort_t* xg        = (ushort_t*)(ws + OFF_XG);
  ushort_t* hbuf      = (ushort_t*)(ws + OFF_HBUF);
  ushort_t* w1bT      = (ushort_t*)(ws + OFF_W1BT);
  ushort_t* w2bT      = (ushort_t*)(ws + OFF_W2BT);
  float*    rowout    = (float*)(ws + OFF_ROWOUT);

  hipMemsetAsync(ws, 0, 40960, stream);

  gate_kernel<<<S_LEN / 4, 256, 0, stream>>>(x, w_gate, b_gate, tok_e, tok_g, ctl);
  scan_kernel<<<1, 64, 0, stream>>>(ctl);
  assign_kernel<<<32, 256, 0, stream>>>(tok_e, ctl, row_token, tok_row);
  gather_kernel<<<ROWS_CAP, 256, 0, stream>>>(x, row_token, xg);
  convT_kernel<<<dim3(H_DIM / 32, D_DIM / 64, E_NUM), dim3(32, 8), 0, stream>>>(w1, w1bT, D_DIM, H_DIM);
  convT_kernel<<<dim3(D_DIM / 32, H_DIM / 64, E_NUM), dim3(32, 8), 0, stream>>>(w2, w2bT, H_DIM, D_DIM);
  gemm1_kernel<<<dim3(MBLK, H_DIM / 128), 256, 0, stream>>>(xg, w1bT, b1, hbuf, ctl);
  gemm2_kernel<<<dim3(MBLK, D_DIM / 128), 256, 0, stream>>>(hbuf, w2bT, rowout, ctl);
  combine_kernel<<<S_LEN, 256, 0, stream>>>(rowout, b2, tok_e, tok_g, tok_row, out);
}

// Round 5
// 449.542 us; speedup vs baseline: 2.1450x; 1.3016x over previous
//
#include <hip/hip_runtime.h>
#include <stdint.h>

typedef unsigned short ushort_t;
typedef short s16x8 __attribute__((ext_vector_type(8)));
typedef float f32x4 __attribute__((ext_vector_type(4)));

#define S_LEN 4096
#define D_DIM 1024
#define H_DIM 2816
#define E_NUM 8
#define ROWS_CAP 9216   // 72 * 128
#define MBLK 72
#define LDSPAD 72       // 64 + 8 shorts -> 144B row stride (16B aligned, bank-spread)

// ---- workspace layout (bytes) ----
#define OFF_CTL      0         // baseP[8]@128, countP[8]@192, mblk_e[72]@256
#define OFF_ROWTOK   1024      // int[ROWS_CAP]   (zeroed: pad rows -> token 0)
#define OFF_TOKE     81920     // int[S*2]
#define OFF_TOKG     114688    // float[S*2]
#define OFF_TOKROW   147456    // int[S*2]
#define OFF_XG       262144                                  // bf16 [ROWS_CAP][D]
#define OFF_HBUF     (OFF_XG + (size_t)ROWS_CAP*D_DIM*2)     // bf16 [ROWS_CAP][H]
#define OFF_W1BT     (OFF_HBUF + (size_t)ROWS_CAP*H_DIM*2)   // bf16 [E][H][D]
#define OFF_W2BT     (OFF_W1BT + (size_t)E_NUM*D_DIM*H_DIM*2)// bf16 [E][D][H]
#define OFF_ROWOUT   OFF_W1BT  // fp32 [ROWS_CAP][D] aliases w1bT (dead after gemm1)

__device__ __forceinline__ ushort_t f2bf(float f) {
  unsigned int u = __float_as_uint(f);
  unsigned int r = (u + 0x7fffu + ((u >> 16) & 1u)) >> 16;
  return (ushort_t)r;
}

// ---------- gating: NO atomics (8-counter cacheline atomics cost ~100us) ----------
__global__ void gate_kernel(const float* __restrict__ x, const float* __restrict__ wg,
                            const float* __restrict__ bg, int* __restrict__ tok_e,
                            float* __restrict__ tok_g) {
  int wave = threadIdx.x >> 6;
  int lane = threadIdx.x & 63;
  int s = blockIdx.x * 4 + wave;
  float acc[8];
#pragma unroll
  for (int e = 0; e < 8; e++) acc[e] = 0.f;
  const float* xr = x + (size_t)s * D_DIM;
  for (int d = lane; d < D_DIM; d += 64) {
    float xv = xr[d];
    const float4* w = (const float4*)(wg + (size_t)d * 8);
    float4 w0 = w[0], w1 = w[1];
    acc[0] += xv * w0.x; acc[1] += xv * w0.y; acc[2] += xv * w0.z; acc[3] += xv * w0.w;
    acc[4] += xv * w1.x; acc[5] += xv * w1.y; acc[6] += xv * w1.z; acc[7] += xv * w1.w;
  }
#pragma unroll
  for (int e = 0; e < 8; e++) {
    for (int off = 32; off > 0; off >>= 1) acc[e] += __shfl_xor(acc[e], off, 64);
  }
  if (lane == 0) {
    float l[8];
#pragma unroll
    for (int e = 0; e < 8; e++) l[e] = acc[e] + bg[e];
    int e0 = 0;
#pragma unroll
    for (int e = 1; e < 8; e++) if (l[e] > l[e0]) e0 = e;
    int e1 = (e0 == 0) ? 1 : 0;
#pragma unroll
    for (int e = 0; e < 8; e++) if (e != e0 && l[e] > l[e1]) e1 = e;
    float t = __expf(l[e1] - l[e0]);
    float p1 = t / (1.f + t);
    float p0 = 1.f - p1;
    tok_e[s * 2] = e0; tok_e[s * 2 + 1] = e1;
    tok_g[s * 2] = p0; tok_g[s * 2 + 1] = p1;
  }
}

// ---------- routing: single block, zero global atomics ----------
// Packed 8x16-bit histograms in 2 ulongs -> shfl scan -> LDS cursors.
__global__ __launch_bounds__(256) void route_kernel(
    const int* __restrict__ tok_e, int* __restrict__ ctl,
    int* __restrict__ row_token, int* __restrict__ tok_row) {
  __shared__ unsigned long long wsum01[4], wsum23[4];
  __shared__ int offs[256][9];   // 9-stride: bank-spread (9 coprime 32)
  int tid = threadIdx.x;
  int lane = tid & 63, wave = tid >> 6;

  int elist[32];
  unsigned long long c01 = 0, c23 = 0;
#pragma unroll
  for (int k = 0; k < 32; k++) {
    int e = tok_e[k * 256 + tid];
    elist[k] = e;
    if (e < 4) c01 += 1ull << (e * 16);
    else       c23 += 1ull << ((e - 4) * 16);
  }
  // wave inclusive scan
  unsigned long long s01 = c01, s23 = c23;
  for (int off = 1; off < 64; off <<= 1) {
    unsigned long long t01 = __shfl_up(s01, off, 64);
    unsigned long long t23 = __shfl_up(s23, off, 64);
    if (lane >= off) { s01 += t01; s23 += t23; }
  }
  if (lane == 63) { wsum01[wave] = s01; wsum23[wave] = s23; }
  __syncthreads();
  unsigned long long p01 = 0, p23 = 0, g01 = 0, g23 = 0;
#pragma unroll
  for (int w = 0; w < 4; w++) {
    unsigned long long a = wsum01[w], b = wsum23[w];
    if (w < wave) { p01 += a; p23 += b; }
    g01 += a; g23 += b;
  }
  unsigned long long e01 = p01 + s01 - c01;   // exclusive prefix, this thread
  unsigned long long e23 = p23 + s23 - c23;

  int base_a[8], cp_a[8];
  int run = 0;
#pragma unroll
  for (int e = 0; e < 8; e++) {
    int tote = (e < 4) ? (int)((g01 >> (e * 16)) & 0xffff)
                       : (int)((g23 >> ((e - 4) * 16)) & 0xffff);
    int exe  = (e < 4) ? (int)((e01 >> (e * 16)) & 0xffff)
                       : (int)((e23 >> ((e - 4) * 16)) & 0xffff);
    int cp = (tote + 127) & ~127;
    base_a[e] = run; cp_a[e] = cp;
    offs[tid][e] = run + exe;
    run += cp;
  }
  if (tid < 8) { ctl[32 + tid] = base_a[tid]; ctl[48 + tid] = cp_a[tid]; }
  if (tid < MBLK) {
    int r = tid * 128, ee = -1;
#pragma unroll
    for (int q = 0; q < 8; q++)
      if (r >= base_a[q] && r < base_a[q] + cp_a[q]) ee = q;
    ctl[64 + tid] = ee;
  }
  __syncthreads();
#pragma unroll
  for (int k = 0; k < 32; k++) {
    int i = k * 256 + tid;
    int e = elist[k];
    int r = offs[tid][e]++;
    row_token[r] = i >> 1;
    tok_row[i] = r;
  }
}

// ---------- gather x rows into expert-sorted bf16 ----------
__global__ void gather_kernel(const float* __restrict__ x, const int* __restrict__ row_token,
                              ushort_t* __restrict__ xg) {
  int row = blockIdx.x;
  int t = row_token[row];
  float4 v = ((const float4*)(x + (size_t)t * D_DIM))[threadIdx.x];
  uint2 o;
  o.x = (unsigned)f2bf(v.x) | ((unsigned)f2bf(v.y) << 16);
  o.y = (unsigned)f2bf(v.z) | ((unsigned)f2bf(v.w) << 16);
  *(uint2*)(xg + (size_t)row * D_DIM + threadIdx.x * 4) = o;
}

// ---------- fp32 [E][R][C] -> bf16 [E][C][R] ----------
__global__ void convT_kernel(const float* __restrict__ in, ushort_t* __restrict__ out,
                             int R, int C) {
  __shared__ float t[64][33];
  size_t base = (size_t)blockIdx.z * R * C;
  int c = blockIdx.x * 32 + threadIdx.x;
#pragma unroll
  for (int i = 0; i < 64; i += 8) {
    int r = blockIdx.y * 64 + threadIdx.y + i;
    t[threadIdx.y + i][threadIdx.x] = in[base + (size_t)r * C + c];
  }
  __syncthreads();
  int rr = blockIdx.y * 64 + threadIdx.x * 2;
#pragma unroll
  for (int i = 0; i < 32; i += 8) {
    int cc = blockIdx.x * 32 + threadIdx.y + i;
    unsigned lo = f2bf(t[threadIdx.x * 2][threadIdx.y + i]);
    unsigned hi = f2bf(t[threadIdx.x * 2 + 1][threadIdx.y + i]);
    *(unsigned*)(out + base + (size_t)cc * R + rr) = lo | (hi << 16);
  }
}

// ================= register-pipelined 128x128xBK64 GEMM bodies =================
#define GEMM_PIPE(KDIM)                                                          \
  __shared__ __align__(16) short As[128 * LDSPAD];                               \
  __shared__ __align__(16) short Bs[128 * LDSPAD];                               \
  int tid = threadIdx.x;                                                         \
  int wave = tid >> 6, lane = tid & 63;                                          \
  int wm = wave >> 1, wn = wave & 1;                                             \
  int m16 = lane & 15, quad = lane >> 4;                                         \
  int srow = lane >> 3;          /* 0..7 */                                      \
  int scol = (lane & 7) * 8;     /* shorts, 16B chunks */                        \
  const ushort_t* Ap = Ab + (size_t)(wave * 32 + srow) * KDIM + scol;            \
  const ushort_t* Bp = Bb + (size_t)(wave * 32 + srow) * KDIM + scol;            \
  short* Aw = As + (wave * 32 + srow) * LDSPAD + scol;                           \
  short* Bw = Bs + (wave * 32 + srow) * LDSPAD + scol;                           \
  f32x4 acc[4][4];                                                               \
  _Pragma("unroll") for (int i = 0; i < 4; i++)                                  \
  _Pragma("unroll") for (int j = 0; j < 4; j++)                                  \
      acc[i][j] = (f32x4){0.f, 0.f, 0.f, 0.f};                                   \
  s16x8 Ar[4], Br[4];                                                            \
  _Pragma("unroll") for (int c = 0; c < 4; c++) {                                \
    Ar[c] = *(const s16x8*)(Ap + (size_t)c * 8 * KDIM);                          \
    Br[c] = *(const s16x8*)(Bp + (size_t)c * 8 * KDIM);                          \
  }                                                                              \
  const int nk = KDIM / 64;                                                      \
  for (int it = 0; it < nk; ++it) {                                              \
    __syncthreads();                                                             \
    _Pragma("unroll") for (int c = 0; c < 4; c++) {                              \
      *(s16x8*)(Aw + c * 8 * LDSPAD) = Ar[c];                                    \
      *(s16x8*)(Bw + c * 8 * LDSPAD) = Br[c];                                    \
    }                                                                            \
    __syncthreads();                                                             \
    if (it + 1 < nk) {                                                           \
      const ushort_t* Ap2 = Ap + (it + 1) * 64;                                  \
      const ushort_t* Bp2 = Bp + (it + 1) * 64;                                  \
      _Pragma("unroll") for (int c = 0; c < 4; c++) {                            \
        Ar[c] = *(const s16x8*)(Ap2 + (size_t)c * 8 * KDIM);                     \
        Br[c] = *(const s16x8*)(Bp2 + (size_t)c * 8 * KDIM);                     \
      }                                                                          \
    }                                                                            \
    _Pragma("unroll") for (int kc = 0; kc < 2; kc++) {                           \
      s16x8 a[4], b[4];                                                          \
      _Pragma("unroll") for (int i = 0; i < 4; i++)                              \
        a[i] = *(const s16x8*)(As + (wm * 64 + i * 16 + m16) * LDSPAD +          \
                               kc * 32 + quad * 8);                              \
      _Pragma("unroll") for (int j = 0; j < 4; j++)                              \
        b[j] = *(const s16x8*)(Bs + (wn * 64 + j * 16 + m16) * LDSPAD +          \
                               kc * 32 + quad * 8);                              \
      _Pragma("unroll") for (int i = 0; i < 4; i++)                              \
      _Pragma("unroll") for (int j = 0; j < 4; j++)                              \
          acc[i][j] = __builtin_amdgcn_mfma_f32_16x16x32_bf16(b[j], a[i],        \
                                                              acc[i][j], 0, 0, 0);\
    }                                                                            \
  }

// ---------- GEMM1: h = silu(xg @ w1bT-tile + b1) ----------
__global__ __launch_bounds__(256) void gemm1_kernel(
    const ushort_t* __restrict__ xg, const ushort_t* __restrict__ w1bT,
    const float* __restrict__ b1, ushort_t* __restrict__ hbuf, const int* __restrict__ ctl) {
  int e = ctl[64 + blockIdx.x];
  if (e < 0) return;
  int rowbase = blockIdx.x * 128;
  const ushort_t* Ab = xg + (size_t)rowbase * D_DIM;
  const ushort_t* Bb = w1bT + ((size_t)e * H_DIM + (size_t)blockIdx.y * 128) * D_DIM;

  GEMM_PIPE(D_DIM)

  const float* b1e = b1 + (size_t)e * H_DIM;
#pragma unroll
  for (int i = 0; i < 4; i++) {
    int rowg = rowbase + wm * 64 + i * 16 + m16;
#pragma unroll
    for (int j = 0; j < 4; j++) {
      int h = blockIdx.y * 128 + wn * 64 + j * 16 + quad * 4;
      float4 bb = *(const float4*)(b1e + h);
      float v0 = acc[i][j][0] + bb.x, v1 = acc[i][j][1] + bb.y;
      float v2 = acc[i][j][2] + bb.z, v3 = acc[i][j][3] + bb.w;
      v0 = v0 / (1.f + __expf(-v0)); v1 = v1 / (1.f + __expf(-v1));
      v2 = v2 / (1.f + __expf(-v2)); v3 = v3 / (1.f + __expf(-v3));
      uint2 o;
      o.x = (unsigned)f2bf(v0) | ((unsigned)f2bf(v1) << 16);
      o.y = (unsigned)f2bf(v2) | ((unsigned)f2bf(v3) << 16);
      *(uint2*)(hbuf + (size_t)rowg * H_DIM + h) = o;
    }
  }
}

// ---------- GEMM2: rowout = h @ w2bT-tile ----------
__global__ __launch_bounds__(256) void gemm2_kernel(
    const ushort_t* __restrict__ hbuf, const ushort_t* __restrict__ w2bT,
    float* __restrict__ rowout, const int* __restrict__ ctl) {
  int e = ctl[64 + blockIdx.x];
  if (e < 0) return;
  int rowbase = blockIdx.x * 128;
  const ushort_t* Ab = hbuf + (size_t)rowbase * H_DIM;
  const ushort_t* Bb = w2bT + ((size_t)e * D_DIM + (size_t)blockIdx.y * 128) * H_DIM;

  GEMM_PIPE(H_DIM)

#pragma unroll
  for (int i = 0; i < 4; i++) {
    int rowg = rowbase + wm * 64 + i * 16 + m16;
#pragma unroll
    for (int j = 0; j < 4; j++) {
      int d = blockIdx.y * 128 + wn * 64 + j * 16 + quad * 4;
      *(f32x4*)(rowout + (size_t)rowg * D_DIM + d) = acc[i][j];
    }
  }
}

// ---------- combine ----------
__global__ void combine_kernel(const float* __restrict__ rowout, const float* __restrict__ b2,
                               const int* __restrict__ tok_e, const float* __restrict__ tok_g,
                               const int* __restrict__ tok_row, float* __restrict__ out) {
  int s = blockIdx.x;
  int e0 = tok_e[s * 2], e1 = tok_e[s * 2 + 1];
  float g0 = tok_g[s * 2], g1 = tok_g[s * 2 + 1];
  int r0 = tok_row[s * 2], r1 = tok_row[s * 2 + 1];
  int d = threadIdx.x * 4;
  float4 a = *(const float4*)(rowout + (size_t)r0 * D_DIM + d);
  float4 b = *(const float4*)(rowout + (size_t)r1 * D_DIM + d);
  float4 c0 = *(const float4*)(b2 + (size_t)e0 * D_DIM + d);
  float4 c1 = *(const float4*)(b2 + (size_t)e1 * D_DIM + d);
  float4 o;
  o.x = g0 * (a.x + c0.x) + g1 * (b.x + c1.x);
  o.y = g0 * (a.y + c0.y) + g1 * (b.y + c1.y);
  o.z = g0 * (a.z + c0.z) + g1 * (b.z + c1.z);
  o.w = g0 * (a.w + c0.w) + g1 * (b.w + c1.w);
  *(float4*)(out + (size_t)s * D_DIM + d) = o;
}

extern "C" void kernel_launch(void* const* d_in, const int* in_sizes, int n_in,
                              void* d_out, int out_size, void* d_ws, size_t ws_size,
                              hipStream_t stream) {
  const float* x      = (const float*)d_in[0];
  const float* w_gate = (const float*)d_in[1];
  const float* b_gate = (const float*)d_in[2];
  const float* w1     = (const float*)d_in[3];
  const float* b1     = (const float*)d_in[4];
  const float* w2     = (const float*)d_in[5];
  const float* b2     = (const float*)d_in[6];
  float* out = (float*)d_out;
  char* ws = (char*)d_ws;

  int*      ctl       = (int*)(ws + OFF_CTL);
  int*      row_token = (int*)(ws + OFF_ROWTOK);
  int*      tok_e     = (int*)(ws + OFF_TOKE);
  float*    tok_g     = (float*)(ws + OFF_TOKG);
  int*      tok_row   = (int*)(ws + OFF_TOKROW);
  ushort_t* xg        = (ushort_t*)(ws + OFF_XG);
  ushort_t* hbuf      = (ushort_t*)(ws + OFF_HBUF);
  ushort_t* w1bT      = (ushort_t*)(ws + OFF_W1BT);
  ushort_t* w2bT      = (ushort_t*)(ws + OFF_W2BT);
  float*    rowout    = (float*)(ws + OFF_ROWOUT);

  // zero ctl + row_token (pad rows must map to token 0; ws is poisoned 0xAA)
  hipMemsetAsync(ws, 0, 40960, stream);

  gate_kernel<<<S_LEN / 4, 256, 0, stream>>>(x, w_gate, b_gate, tok_e, tok_g);
  route_kernel<<<1, 256, 0, stream>>>(tok_e, ctl, row_token, tok_row);
  gather_kernel<<<ROWS_CAP, 256, 0, stream>>>(x, row_token, xg);
  convT_kernel<<<dim3(H_DIM / 32, D_DIM / 64, E_NUM), dim3(32, 8), 0, stream>>>(w1, w1bT, D_DIM, H_DIM);
  convT_kernel<<<dim3(D_DIM / 32, H_DIM / 64, E_NUM), dim3(32, 8), 0, stream>>>(w2, w2bT, H_DIM, D_DIM);
  gemm1_kernel<<<dim3(MBLK, H_DIM / 128), 256, 0, stream>>>(xg, w1bT, b1, hbuf, ctl);
  gemm2_kernel<<<dim3(MBLK, D_DIM / 128), 256, 0, stream>>>(hbuf, w2bT, rowout, ctl);
  combine_kernel<<<S_LEN, 256, 0, stream>>>(rowout, b2, tok_e, tok_g, tok_row, out);
}